// Round 2
// 855.301 us; speedup vs baseline: 1.0717x; 1.0717x over previous
//
#include <hip/hip_runtime.h>

#define BB 64
#define TT 1024
#define DD 256
#define HH 256
#define CH 8             // timesteps per LDS chunk
#define NCH (TT / CH)    // 128 chunks

typedef float vf4 __attribute__((ext_vector_type(4)));
typedef float vf2 __attribute__((ext_vector_type(2)));
struct alignas(16) v2x2 { vf2 lo, hi; };   // one 16-B load, two pk-operands

#define LD4(p) (*(const vf4*)(p))
#define LD2(p) (*(const vf2*)(p))
#define LDW(p) (*(const v2x2*)(p))

// tanh(x) = 1 - 2/(e^{2x}+1); saturates correctly for large |x|.
__device__ __forceinline__ float fast_tanh(float x) {
    float e = __expf(2.0f * x);
    return 1.0f - 2.0f / (e + 1.0f);
}

// float2 FMA: selects v_pk_fma_f32 on gfx950 (exact fp32, 2x rate).
#define PKFMA(acc, aa, bb) acc = __builtin_elementwise_fma((aa), (bb), (acc))

// dst = src + dpp_shuffle(src). VALU-pipe cross-lane (no LDS traffic).
// CTRL: 0xB1 quad_perm xor1, 0x4E quad_perm xor2, 0x124 row_ror:4, 0x128 row_ror:8.
#define DPPADD(dst, src, CTRL) {                                                   \
    int _di = __builtin_amdgcn_update_dpp(0, __float_as_int(src), CTRL, 0xF, 0xF, true); \
    dst = (src) + __int_as_float(_di); }

// NOTE: macro params must NOT be named x/y/z/w (component-accessor capture).
#define FMR(rr, bb, ss)                   \
    rr.x = fmaf((ss), (bb).x, rr.x);      \
    rr.y = fmaf((ss), (bb).y, rr.y);      \
    rr.z = fmaf((ss), (bb).z, rr.z);      \
    rr.w = fmaf((ss), (bb).w, rr.w)

// ---------------------------------------------------------------------------
// Phase 1 (unchanged, ~160 us): xp = x * W_ih^T + b_ih, tiled GEMM.
// ---------------------------------------------------------------------------
#define BKb 32
#define LDP 132

__global__ __attribute__((amdgpu_flat_work_group_size(256, 256),
                          amdgpu_waves_per_eu(4, 4)))
void xproj_kernel(const float* __restrict__ x, const float* __restrict__ W_ih,
                  const float* __restrict__ b_ih, float* __restrict__ xp)
{
    __shared__ float As[BKb][LDP];
    __shared__ float Bs[BKb][LDP];

    const int tid = threadIdx.x;
    const int nb = blockIdx.x & 1;
    const int mb = blockIdx.x >> 1;
    const int m0 = mb * 128;
    const int n0 = nb * 128;

    const int sr = tid >> 3;
    const int sk = (tid & 7) * 4;

    const int tx = tid & 15;
    const int ty = tid >> 4;
    const int ma = ty * 4, mh = 64 + ty * 4;
    const int na = tx * 4, nh = 64 + tx * 4;

    vf4 ra0 = 0, ra1 = 0, ra2 = 0, ra3 = 0, ra4 = 0, ra5 = 0, ra6 = 0, ra7 = 0;
    vf4 rb0 = 0, rb1 = 0, rb2 = 0, rb3 = 0, rb4 = 0, rb5 = 0, rb6 = 0, rb7 = 0;

    for (int k0 = 0; k0 < DD; k0 += BKb) {
        #pragma unroll
        for (int g = 0; g < 4; ++g) {
            const int r = sr + g * 32;
            const vf4 v = LD4(x + (size_t)(m0 + r) * DD + k0 + sk);
            As[sk + 0][r] = v.x; As[sk + 1][r] = v.y;
            As[sk + 2][r] = v.z; As[sk + 3][r] = v.w;
        }
        #pragma unroll
        for (int g = 0; g < 4; ++g) {
            const int n = sr + g * 32;
            const vf4 v = LD4(W_ih + (size_t)(n0 + n) * DD + k0 + sk);
            Bs[sk + 0][n] = v.x; Bs[sk + 1][n] = v.y;
            Bs[sk + 2][n] = v.z; Bs[sk + 3][n] = v.w;
        }
        __syncthreads();

        #pragma unroll
        for (int kk = 0; kk < BKb; ++kk) {
            const vf4 alo = LD4(&As[kk][ma]);
            const vf4 ahi = LD4(&As[kk][mh]);
            const vf4 bl  = LD4(&Bs[kk][na]);
            const vf4 bh  = LD4(&Bs[kk][nh]);
            FMR(ra0, bl, alo.x); FMR(rb0, bh, alo.x);
            FMR(ra1, bl, alo.y); FMR(rb1, bh, alo.y);
            FMR(ra2, bl, alo.z); FMR(rb2, bh, alo.z);
            FMR(ra3, bl, alo.w); FMR(rb3, bh, alo.w);
            FMR(ra4, bl, ahi.x); FMR(rb4, bh, ahi.x);
            FMR(ra5, bl, ahi.y); FMR(rb5, bh, ahi.y);
            FMR(ra6, bl, ahi.z); FMR(rb6, bh, ahi.z);
            FMR(ra7, bl, ahi.w); FMR(rb7, bh, ahi.w);
        }
        __syncthreads();
    }

    const vf4 bia = LD4(b_ih + n0 + na);
    const vf4 bib = LD4(b_ih + n0 + nh);

    #define STORE_ROW(m, rA, rB)                                   \
        {                                                          \
            float* outp = xp + (size_t)(m0 + (m)) * HH + n0;       \
            *(vf4*)(outp + na) = rA + bia;                         \
            *(vf4*)(outp + nh) = rB + bib;                         \
        }
    STORE_ROW(ma + 0, ra0, rb0); STORE_ROW(ma + 1, ra1, rb1);
    STORE_ROW(ma + 2, ra2, rb2); STORE_ROW(ma + 3, ra3, rb3);
    STORE_ROW(mh + 0, ra4, rb4); STORE_ROW(mh + 1, ra5, rb5);
    STORE_ROW(mh + 2, ra6, rb6); STORE_ROW(mh + 3, ra7, rb7);
    #undef STORE_ROW
}

// ---------------------------------------------------------------------------
// Phase 2: recurrence, one WG per batch (64 WGs, 1024 threads).
// Same compute core as before (Jt=4 x Kt=16, DPP reduction). KEY change:
// hipcc emits `s_waitcnt vmcnt(0) lgkmcnt(0)` before every s_barrier, so ANY
// per-step global load/store gets its FULL latency exposed on every step's
// __syncthreads (this is why the old "prefetch 2 ahead" never helped).
// Fix: zero global memory ops inside the steady-state step.
//   - xp staged through LDS in double-buffered 8-step chunks (contiguous
//     8 KB => one coalesced dwordx2 per thread per chunk, issued 2 chunks
//     ahead; latency amortized over 8 steps).
//   - h outputs staged in a double-buffered LDS chunk, flushed once per
//     8 steps with coalesced dwordx2 stores.
//   - chunk body fully unrolled: hbuf parity + all LDS offsets become
//     compile-time immediates; per-step pointer math deleted.
// LDS total: 2560 + 2*8KB + 2*8KB = 35,328 B (< 64 KB per-WG static limit;
// the round-0 CH=16 variant was 68 KB — possible launch-failure cause).
// ---------------------------------------------------------------------------
__global__ __attribute__((amdgpu_flat_work_group_size(1024, 1024),
                          amdgpu_waves_per_eu(4, 4)))
void rnn_kernel(const float* __restrict__ W_hh, const float* __restrict__ b_hh,
                const float* __restrict__ xpin, float* __restrict__ hout)
{
    const int tid = threadIdx.x;
    const int jg = tid >> 4;          // 0..63: group of 4 outputs
    const int c  = tid & 15;          // 0..15: k-chunk (16 floats)
    const int j0 = jg * 4;
    const int jmine = j0 + (c & 3);   // the output this lane finalizes
    const int b = blockIdx.x;

    __shared__ float hbuf[2][16 * 20];     // h[k] at word (k>>4)*20 + (k&15)
    __shared__ float xchk[2][CH * HH];     // xp chunk double-buffer (2 x 8 KB)
    __shared__ float obuf[2][CH * HH];     // output staging double-buffer (2 x 8 KB)

    const float* wr0 = W_hh + (size_t)(j0 + 0) * HH + c * 16;
    const float* wr1 = W_hh + (size_t)(j0 + 1) * HH + c * 16;
    const float* wr2 = W_hh + (size_t)(j0 + 2) * HH + c * 16;
    const float* wr3 = W_hh + (size_t)(j0 + 3) * HH + c * 16;
    v2x2 w00 = LDW(wr0 + 0), w01 = LDW(wr0 + 4), w02 = LDW(wr0 + 8), w03 = LDW(wr0 + 12);
    v2x2 w10 = LDW(wr1 + 0), w11 = LDW(wr1 + 4), w12 = LDW(wr1 + 8), w13 = LDW(wr1 + 12);
    v2x2 w20 = LDW(wr2 + 0), w21 = LDW(wr2 + 4), w22 = LDW(wr2 + 8), w23 = LDW(wr2 + 12);
    v2x2 w30 = LDW(wr3 + 0), w31 = LDW(wr3 + 4), w32 = LDW(wr3 + 8), w33 = LDW(wr3 + 12);
    const float bias = b_hh[jmine];

    const float* xbase = xpin + (size_t)b * TT * HH;
    float*       obase = hout + (size_t)b * TT * HH;
    const int haddr = ((jmine >> 4) * 20) + (jmine & 15);   // LDS slot for jmine

    // ---- prologue: chunk 0 into LDS, chunk 1 into registers (in flight) ----
    vf2 r = LD2(xbase + tid * 2);                 // chunk 0 (2048 floats, 2/thread)
    if (tid < 320) hbuf[0][tid] = 0.0f;           // h_0 = 0 (pads incl.)
    *(vf2*)&xchk[0][tid * 2] = r;                 // (compiler inserts vmcnt wait)
    r = LD2(xbase + CH * HH + tid * 2);           // chunk 1, stays in flight
    __syncthreads();

    for (int ci = 0; ci < NCH; ++ci) {
        const int cb = ci & 1;

        #pragma unroll
        for (int s = 0; s < CH; ++s) {
            // Pin weights live each iteration (defeat sinking/remat).
            asm volatile("" : "+v"(w00.lo), "+v"(w00.hi), "+v"(w01.lo), "+v"(w01.hi),
                              "+v"(w02.lo), "+v"(w02.hi), "+v"(w03.lo), "+v"(w03.hi),
                              "+v"(w10.lo), "+v"(w10.hi), "+v"(w11.lo), "+v"(w11.hi),
                              "+v"(w12.lo), "+v"(w12.hi), "+v"(w13.lo), "+v"(w13.hi));
            asm volatile("" : "+v"(w20.lo), "+v"(w20.hi), "+v"(w21.lo), "+v"(w21.hi),
                              "+v"(w22.lo), "+v"(w22.hi), "+v"(w23.lo), "+v"(w23.hi),
                              "+v"(w30.lo), "+v"(w30.hi), "+v"(w31.lo), "+v"(w31.hi),
                              "+v"(w32.lo), "+v"(w32.hi), "+v"(w33.lo), "+v"(w33.hi));

            // xp for this step: LDS broadcast read, immediate offset (s static).
            const float xpv = xchk[cb][s * HH + jmine];

            const float* hc = &hbuf[s & 1][c * 20];    // s static => static buffer
            const v2x2 h0 = LDW(hc + 0), h1 = LDW(hc + 4),
                       h2 = LDW(hc + 8), h3 = LDW(hc + 12);

            vf2 a0 = {0.f, 0.f}, a1 = {0.f, 0.f}, a2 = {0.f, 0.f}, a3 = {0.f, 0.f};
            PKFMA(a0, w00.lo, h0.lo); PKFMA(a1, w10.lo, h0.lo);
            PKFMA(a2, w20.lo, h0.lo); PKFMA(a3, w30.lo, h0.lo);
            PKFMA(a0, w00.hi, h0.hi); PKFMA(a1, w10.hi, h0.hi);
            PKFMA(a2, w20.hi, h0.hi); PKFMA(a3, w30.hi, h0.hi);
            PKFMA(a0, w01.lo, h1.lo); PKFMA(a1, w11.lo, h1.lo);
            PKFMA(a2, w21.lo, h1.lo); PKFMA(a3, w31.lo, h1.lo);
            PKFMA(a0, w01.hi, h1.hi); PKFMA(a1, w11.hi, h1.hi);
            PKFMA(a2, w21.hi, h1.hi); PKFMA(a3, w31.hi, h1.hi);
            PKFMA(a0, w02.lo, h2.lo); PKFMA(a1, w12.lo, h2.lo);
            PKFMA(a2, w22.lo, h2.lo); PKFMA(a3, w32.lo, h2.lo);
            PKFMA(a0, w02.hi, h2.hi); PKFMA(a1, w12.hi, h2.hi);
            PKFMA(a2, w22.hi, h2.hi); PKFMA(a3, w32.hi, h2.hi);
            PKFMA(a0, w03.lo, h3.lo); PKFMA(a1, w13.lo, h3.lo);
            PKFMA(a2, w23.lo, h3.lo); PKFMA(a3, w33.lo, h3.lo);
            PKFMA(a0, w03.hi, h3.hi); PKFMA(a1, w13.hi, h3.hi);
            PKFMA(a2, w23.hi, h3.hi); PKFMA(a3, w33.hi, h3.hi);

            const float s0 = a0.x + a0.y, s1 = a1.x + a1.y,
                        s2 = a2.x + a2.y, s3 = a3.x + a3.y;

            float t0, t1, t2, t3, b0v, b1v, u0, u1, vfin;
            DPPADD(t0, s0, 0xB1); DPPADD(t1, s1, 0xB1);
            DPPADD(t2, s2, 0xB1); DPPADD(t3, s3, 0xB1);
            b0v = (c & 1) ? t1 : t0;
            b1v = (c & 1) ? t3 : t2;
            DPPADD(u0, b0v, 0x4E); DPPADD(u1, b1v, 0x4E);
            vfin = (c & 2) ? u1 : u0;
            DPPADD(vfin, vfin, 0x124);
            DPPADD(vfin, vfin, 0x128);

            // Stage next xp chunk into the other LDS buffer (once per chunk;
            // r was loaded ~8 steps ago, so the vmcnt wait here is free).
            if (s == CH - 1 && ci != NCH - 1) {
                *(vf2*)&xchk[cb ^ 1][tid * 2] = r;
            }

            const float hn = fast_tanh(vfin + xpv + bias);
            if (c < 4) {
                hbuf[1 - (s & 1)][haddr] = hn;        // h for next step
                obuf[cb][s * HH + jmine] = hn;        // output staging (LDS)
            }
            __syncthreads();
        }

        // ---- chunk boundary: flush outputs, prefetch chunk ci+2 ----
        // obuf[cb] is complete (post-barrier); next chunk writes obuf[cb^1],
        // so the flush read cannot race.
        const vf2 ov = *(const vf2*)&obuf[cb][tid * 2];
        *(vf2*)(obase + (size_t)ci * CH * HH + tid * 2) = ov;
        if (ci + 2 < NCH) {
            r = LD2(xbase + (size_t)(ci + 2) * CH * HH + tid * 2);
        }
        // These globals drain at the next chunk's first barrier — once per
        // 8 steps, overlapped with step-0 compute (~50 cyc/step amortized).
    }
}

extern "C" void kernel_launch(void* const* d_in, const int* in_sizes, int n_in,
                              void* d_out, int out_size, void* d_ws, size_t ws_size,
                              hipStream_t stream) {
    const float* x    = (const float*)d_in[0];
    const float* W_ih = (const float*)d_in[1];
    const float* W_hh = (const float*)d_in[2];
    const float* b_ih = (const float*)d_in[3];
    const float* b_hh = (const float*)d_in[4];
    float* out = (float*)d_out;

    const size_t xp_bytes = (size_t)BB * TT * HH * sizeof(float);   // 64 MiB
    // Aliased fallback stays correct: xp chunk k is loaded (2 chunks ahead)
    // strictly before out chunk k is flushed.
    float* xp = (ws_size >= xp_bytes) ? (float*)d_ws : out;

    xproj_kernel<<<dim3(512 * 2), dim3(256), 0, stream>>>(x, W_ih, b_ih, xp);
    rnn_kernel<<<dim3(BB), dim3(1024), 0, stream>>>(W_hh, b_hh, xp, out);
}

// Round 3
// 783.715 us; speedup vs baseline: 1.1696x; 1.0913x over previous
//
#include <hip/hip_runtime.h>

#define BB 64
#define TT 1024
#define DD 256
#define HH 256
#define CH 8             // timesteps per LDS chunk
#define NCH (TT / CH)    // 128 chunks

typedef float vf4 __attribute__((ext_vector_type(4)));
typedef float vf2 __attribute__((ext_vector_type(2)));
struct alignas(16) v2x2 { vf2 lo, hi; };   // one 16-B load, two pk-operands

#define LD4(p) (*(const vf4*)(p))
#define LD2(p) (*(const vf2*)(p))
#define LDW(p) (*(const v2x2*)(p))

// tanh(x) = 1 - 2/(e^{2x}+1); saturates correctly for large |x|.
__device__ __forceinline__ float fast_tanh(float x) {
    float e = __expf(2.0f * x);
    return 1.0f - 2.0f / (e + 1.0f);
}

// float2 FMA: selects v_pk_fma_f32 on gfx950 (exact fp32, 2x rate).
#define PKFMA(acc, aa, bb) acc = __builtin_elementwise_fma((aa), (bb), (acc))

// dst = src + dpp_shuffle(src). VALU-pipe cross-lane (no LDS traffic).
// CTRL: 0xB1 quad_perm xor1, 0x4E quad_perm xor2, 0x124 row_ror:4, 0x128 row_ror:8.
#define DPPADD(dst, src, CTRL) {                                                   \
    int _di = __builtin_amdgcn_update_dpp(0, __float_as_int(src), CTRL, 0xF, 0xF, true); \
    dst = (src) + __int_as_float(_di); }

// NOTE: macro params must NOT be named x/y/z/w (component-accessor capture).
#define FMR(rr, bb, ss)                   \
    rr.x = fmaf((ss), (bb).x, rr.x);      \
    rr.y = fmaf((ss), (bb).y, rr.y);      \
    rr.z = fmaf((ss), (bb).z, rr.z);      \
    rr.w = fmaf((ss), (bb).w, rr.w)

// ---------------------------------------------------------------------------
// Phase 1 (unchanged, ~160 us): xp = x * W_ih^T + b_ih, tiled GEMM.
// ---------------------------------------------------------------------------
#define BKb 32
#define LDP 132

__global__ __attribute__((amdgpu_flat_work_group_size(256, 256),
                          amdgpu_waves_per_eu(4, 4)))
void xproj_kernel(const float* __restrict__ x, const float* __restrict__ W_ih,
                  const float* __restrict__ b_ih, float* __restrict__ xp)
{
    __shared__ float As[BKb][LDP];
    __shared__ float Bs[BKb][LDP];

    const int tid = threadIdx.x;
    const int nb = blockIdx.x & 1;
    const int mb = blockIdx.x >> 1;
    const int m0 = mb * 128;
    const int n0 = nb * 128;

    const int sr = tid >> 3;
    const int sk = (tid & 7) * 4;

    const int tx = tid & 15;
    const int ty = tid >> 4;
    const int ma = ty * 4, mh = 64 + ty * 4;
    const int na = tx * 4, nh = 64 + tx * 4;

    vf4 ra0 = 0, ra1 = 0, ra2 = 0, ra3 = 0, ra4 = 0, ra5 = 0, ra6 = 0, ra7 = 0;
    vf4 rb0 = 0, rb1 = 0, rb2 = 0, rb3 = 0, rb4 = 0, rb5 = 0, rb6 = 0, rb7 = 0;

    for (int k0 = 0; k0 < DD; k0 += BKb) {
        #pragma unroll
        for (int g = 0; g < 4; ++g) {
            const int r = sr + g * 32;
            const vf4 v = LD4(x + (size_t)(m0 + r) * DD + k0 + sk);
            As[sk + 0][r] = v.x; As[sk + 1][r] = v.y;
            As[sk + 2][r] = v.z; As[sk + 3][r] = v.w;
        }
        #pragma unroll
        for (int g = 0; g < 4; ++g) {
            const int n = sr + g * 32;
            const vf4 v = LD4(W_ih + (size_t)(n0 + n) * DD + k0 + sk);
            Bs[sk + 0][n] = v.x; Bs[sk + 1][n] = v.y;
            Bs[sk + 2][n] = v.z; Bs[sk + 3][n] = v.w;
        }
        __syncthreads();

        #pragma unroll
        for (int kk = 0; kk < BKb; ++kk) {
            const vf4 alo = LD4(&As[kk][ma]);
            const vf4 ahi = LD4(&As[kk][mh]);
            const vf4 bl  = LD4(&Bs[kk][na]);
            const vf4 bh  = LD4(&Bs[kk][nh]);
            FMR(ra0, bl, alo.x); FMR(rb0, bh, alo.x);
            FMR(ra1, bl, alo.y); FMR(rb1, bh, alo.y);
            FMR(ra2, bl, alo.z); FMR(rb2, bh, alo.z);
            FMR(ra3, bl, alo.w); FMR(rb3, bh, alo.w);
            FMR(ra4, bl, ahi.x); FMR(rb4, bh, ahi.x);
            FMR(ra5, bl, ahi.y); FMR(rb5, bh, ahi.y);
            FMR(ra6, bl, ahi.z); FMR(rb6, bh, ahi.z);
            FMR(ra7, bl, ahi.w); FMR(rb7, bh, ahi.w);
        }
        __syncthreads();
    }

    const vf4 bia = LD4(b_ih + n0 + na);
    const vf4 bib = LD4(b_ih + n0 + nh);

    #define STORE_ROW(m, rA, rB)                                   \
        {                                                          \
            float* outp = xp + (size_t)(m0 + (m)) * HH + n0;       \
            *(vf4*)(outp + na) = rA + bia;                         \
            *(vf4*)(outp + nh) = rB + bib;                         \
        }
    STORE_ROW(ma + 0, ra0, rb0); STORE_ROW(ma + 1, ra1, rb1);
    STORE_ROW(ma + 2, ra2, rb2); STORE_ROW(ma + 3, ra3, rb3);
    STORE_ROW(mh + 0, ra4, rb4); STORE_ROW(mh + 1, ra5, rb5);
    STORE_ROW(mh + 2, ra6, rb6); STORE_ROW(mh + 3, ra7, rb7);
    #undef STORE_ROW
}

// ---------------------------------------------------------------------------
// Phase 2: recurrence, one WG per batch (64 WGs). RESTRUCTURED: 512 threads,
// G=8 outputs/lane x L=16 k-elems/lane (was G=4 x L=16 @ 1024 threads).
// Why: R6 counters showed VALUBusy ~68% on active CUs (~1100 cyc/step of
// VALU issue) vs ~520 static — and VGPR_Count=52 cannot hold the 64 weight
// floats => the per-step asm pins + 128-VGPR cap (waves_per_eu(4,4)) forced
// AGPR/register churn. Fix:
//   - waves_per_eu(2,2) => 256-VGPR budget; weights (128 floats/lane) + h +
//     acc all register-resident, no churn.
//   - asm pins once per CHUNK (outside the unrolled 8-step body).
//   - LDS h-read traffic halved: 32 ds_read_b128/step (was 64).
//   - barrier width halved: 8 waves (was 16).
// Global traffic stays chunk-staged (no per-step global ops).
// ---------------------------------------------------------------------------
__global__ __attribute__((amdgpu_flat_work_group_size(512, 512),
                          amdgpu_waves_per_eu(2, 2)))
void rnn_kernel(const float* __restrict__ W_hh, const float* __restrict__ b_hh,
                const float* __restrict__ xpin, float* __restrict__ hout)
{
    const int tid = threadIdx.x;
    const int jg = tid >> 4;          // 0..31: group of 8 outputs
    const int c  = tid & 15;          // 0..15: k-chunk (16 floats)
    const int j0 = jg * 8;
    const int jmine = j0 + (c & 7);   // the output this lane finalizes (writers: c<8)
    const int b = blockIdx.x;

    __shared__ float hbuf[2][16 * 20];     // h[k] at word (k>>4)*20 + (k&15)
    __shared__ float xchk[2][CH * HH];     // xp chunk double-buffer (2 x 8 KB)
    __shared__ float obuf[2][CH * HH];     // output staging double-buffer (2 x 8 KB)

    // Weights: 8 rows (j0..j0+7) x 16 cols (c*16..c*16+15) = 128 floats/lane.
    v2x2 w[8][4];
    #pragma unroll
    for (int r = 0; r < 8; ++r) {
        const float* wr = W_hh + (size_t)(j0 + r) * HH + c * 16;
        w[r][0] = LDW(wr + 0);  w[r][1] = LDW(wr + 4);
        w[r][2] = LDW(wr + 8);  w[r][3] = LDW(wr + 12);
    }
    const float bias = b_hh[jmine];

    const float* xbase = xpin + (size_t)b * TT * HH;
    float*       obase = hout + (size_t)b * TT * HH;
    const int haddr = ((jmine >> 4) * 20) + (jmine & 15);   // LDS slot for jmine

    // ---- prologue: chunk 0 into LDS, chunk 1 into registers (in flight) ----
    vf4 rpf = LD4(xbase + tid * 4);               // chunk 0 (2048 floats, 4/thread)
    if (tid < 320) hbuf[0][tid] = 0.0f;           // h_0 = 0 (pads incl.)
    *(vf4*)&xchk[0][tid * 4] = rpf;               // (compiler inserts vmcnt wait)
    rpf = LD4(xbase + CH * HH + tid * 4);         // chunk 1, stays in flight
    __syncthreads();

    for (int ci = 0; ci < NCH; ++ci) {
        const int cb = ci & 1;

        // Pin weights live once per chunk (defeat sinking/remat) — NOT per
        // step, so the unrolled body is free of asm boundaries.
        asm volatile("" : "+v"(w[0][0].lo), "+v"(w[0][0].hi), "+v"(w[0][1].lo), "+v"(w[0][1].hi),
                          "+v"(w[0][2].lo), "+v"(w[0][2].hi), "+v"(w[0][3].lo), "+v"(w[0][3].hi),
                          "+v"(w[1][0].lo), "+v"(w[1][0].hi), "+v"(w[1][1].lo), "+v"(w[1][1].hi),
                          "+v"(w[1][2].lo), "+v"(w[1][2].hi), "+v"(w[1][3].lo), "+v"(w[1][3].hi));
        asm volatile("" : "+v"(w[2][0].lo), "+v"(w[2][0].hi), "+v"(w[2][1].lo), "+v"(w[2][1].hi),
                          "+v"(w[2][2].lo), "+v"(w[2][2].hi), "+v"(w[2][3].lo), "+v"(w[2][3].hi),
                          "+v"(w[3][0].lo), "+v"(w[3][0].hi), "+v"(w[3][1].lo), "+v"(w[3][1].hi),
                          "+v"(w[3][2].lo), "+v"(w[3][2].hi), "+v"(w[3][3].lo), "+v"(w[3][3].hi));
        asm volatile("" : "+v"(w[4][0].lo), "+v"(w[4][0].hi), "+v"(w[4][1].lo), "+v"(w[4][1].hi),
                          "+v"(w[4][2].lo), "+v"(w[4][2].hi), "+v"(w[4][3].lo), "+v"(w[4][3].hi),
                          "+v"(w[5][0].lo), "+v"(w[5][0].hi), "+v"(w[5][1].lo), "+v"(w[5][1].hi),
                          "+v"(w[5][2].lo), "+v"(w[5][2].hi), "+v"(w[5][3].lo), "+v"(w[5][3].hi));
        asm volatile("" : "+v"(w[6][0].lo), "+v"(w[6][0].hi), "+v"(w[6][1].lo), "+v"(w[6][1].hi),
                          "+v"(w[6][2].lo), "+v"(w[6][2].hi), "+v"(w[6][3].lo), "+v"(w[6][3].hi),
                          "+v"(w[7][0].lo), "+v"(w[7][0].hi), "+v"(w[7][1].lo), "+v"(w[7][1].hi),
                          "+v"(w[7][2].lo), "+v"(w[7][2].hi), "+v"(w[7][3].lo), "+v"(w[7][3].hi));

        const float* xc = &xchk[cb][0];
        float*       ob = &obuf[cb][0];

        #pragma unroll
        for (int s = 0; s < CH; ++s) {
            // xp for this step: LDS read, immediate offset (s static).
            const float xpb = xc[s * HH + jmine] + bias;

            const float* hc = &hbuf[s & 1][c * 20];    // s static => static buffer
            const v2x2 h0 = LDW(hc + 0), h1 = LDW(hc + 4),
                       h2 = LDW(hc + 8), h3 = LDW(hc + 12);

            vf2 a0 = {0.f, 0.f}, a1 = {0.f, 0.f}, a2 = {0.f, 0.f}, a3 = {0.f, 0.f};
            vf2 a4 = {0.f, 0.f}, a5 = {0.f, 0.f}, a6 = {0.f, 0.f}, a7 = {0.f, 0.f};
            PKFMA(a0, w[0][0].lo, h0.lo); PKFMA(a0, w[0][0].hi, h0.hi);
            PKFMA(a0, w[0][1].lo, h1.lo); PKFMA(a0, w[0][1].hi, h1.hi);
            PKFMA(a0, w[0][2].lo, h2.lo); PKFMA(a0, w[0][2].hi, h2.hi);
            PKFMA(a0, w[0][3].lo, h3.lo); PKFMA(a0, w[0][3].hi, h3.hi);
            PKFMA(a1, w[1][0].lo, h0.lo); PKFMA(a1, w[1][0].hi, h0.hi);
            PKFMA(a1, w[1][1].lo, h1.lo); PKFMA(a1, w[1][1].hi, h1.hi);
            PKFMA(a1, w[1][2].lo, h2.lo); PKFMA(a1, w[1][2].hi, h2.hi);
            PKFMA(a1, w[1][3].lo, h3.lo); PKFMA(a1, w[1][3].hi, h3.hi);
            PKFMA(a2, w[2][0].lo, h0.lo); PKFMA(a2, w[2][0].hi, h0.hi);
            PKFMA(a2, w[2][1].lo, h1.lo); PKFMA(a2, w[2][1].hi, h1.hi);
            PKFMA(a2, w[2][2].lo, h2.lo); PKFMA(a2, w[2][2].hi, h2.hi);
            PKFMA(a2, w[2][3].lo, h3.lo); PKFMA(a2, w[2][3].hi, h3.hi);
            PKFMA(a3, w[3][0].lo, h0.lo); PKFMA(a3, w[3][0].hi, h0.hi);
            PKFMA(a3, w[3][1].lo, h1.lo); PKFMA(a3, w[3][1].hi, h1.hi);
            PKFMA(a3, w[3][2].lo, h2.lo); PKFMA(a3, w[3][2].hi, h2.hi);
            PKFMA(a3, w[3][3].lo, h3.lo); PKFMA(a3, w[3][3].hi, h3.hi);
            PKFMA(a4, w[4][0].lo, h0.lo); PKFMA(a4, w[4][0].hi, h0.hi);
            PKFMA(a4, w[4][1].lo, h1.lo); PKFMA(a4, w[4][1].hi, h1.hi);
            PKFMA(a4, w[4][2].lo, h2.lo); PKFMA(a4, w[4][2].hi, h2.hi);
            PKFMA(a4, w[4][3].lo, h3.lo); PKFMA(a4, w[4][3].hi, h3.hi);
            PKFMA(a5, w[5][0].lo, h0.lo); PKFMA(a5, w[5][0].hi, h0.hi);
            PKFMA(a5, w[5][1].lo, h1.lo); PKFMA(a5, w[5][1].hi, h1.hi);
            PKFMA(a5, w[5][2].lo, h2.lo); PKFMA(a5, w[5][2].hi, h2.hi);
            PKFMA(a5, w[5][3].lo, h3.lo); PKFMA(a5, w[5][3].hi, h3.hi);
            PKFMA(a6, w[6][0].lo, h0.lo); PKFMA(a6, w[6][0].hi, h0.hi);
            PKFMA(a6, w[6][1].lo, h1.lo); PKFMA(a6, w[6][1].hi, h1.hi);
            PKFMA(a6, w[6][2].lo, h2.lo); PKFMA(a6, w[6][2].hi, h2.hi);
            PKFMA(a6, w[6][3].lo, h3.lo); PKFMA(a6, w[6][3].hi, h3.hi);
            PKFMA(a7, w[7][0].lo, h0.lo); PKFMA(a7, w[7][0].hi, h0.hi);
            PKFMA(a7, w[7][1].lo, h1.lo); PKFMA(a7, w[7][1].hi, h1.hi);
            PKFMA(a7, w[7][2].lo, h2.lo); PKFMA(a7, w[7][2].hi, h2.hi);
            PKFMA(a7, w[7][3].lo, h3.lo); PKFMA(a7, w[7][3].hi, h3.hi);

            const float s0 = a0.x + a0.y, s1 = a1.x + a1.y,
                        s2 = a2.x + a2.y, s3 = a3.x + a3.y,
                        s4 = a4.x + a4.y, s5 = a5.x + a5.y,
                        s6 = a6.x + a6.y, s7 = a7.x + a7.y;

            // 16-lane reduce of 8 outputs: xor1 +sel, xor2 +sel, ror4 +sel, ror8.
            float t0, t1, t2, t3, t4, t5, t6, t7;
            DPPADD(t0, s0, 0xB1); DPPADD(t1, s1, 0xB1);
            DPPADD(t2, s2, 0xB1); DPPADD(t3, s3, 0xB1);
            DPPADD(t4, s4, 0xB1); DPPADD(t5, s5, 0xB1);
            DPPADD(t6, s6, 0xB1); DPPADD(t7, s7, 0xB1);
            const float p0 = (c & 1) ? t1 : t0;
            const float p1 = (c & 1) ? t3 : t2;
            const float p2 = (c & 1) ? t5 : t4;
            const float p3 = (c & 1) ? t7 : t6;
            float u0, u1, u2, u3;
            DPPADD(u0, p0, 0x4E); DPPADD(u1, p1, 0x4E);
            DPPADD(u2, p2, 0x4E); DPPADD(u3, p3, 0x4E);
            const float v0 = (c & 2) ? u1 : u0;
            const float v1 = (c & 2) ? u3 : u2;
            float q0, q1;
            DPPADD(q0, v0, 0x124); DPPADD(q1, v1, 0x124);
            float vfin = (c & 4) ? q1 : q0;
            DPPADD(vfin, vfin, 0x128);

            // Stage next xp chunk into the other LDS buffer (once per chunk;
            // rpf was loaded ~8 steps ago, so the vmcnt wait here is free).
            if (s == CH - 1 && ci != NCH - 1) {
                *(vf4*)&xchk[cb ^ 1][tid * 4] = rpf;
            }

            const float hn = fast_tanh(vfin + xpb);
            if (c < 8) {
                hbuf[1 - (s & 1)][haddr] = hn;        // h for next step
                ob[s * HH + jmine] = hn;              // output staging (LDS)
            }
            __syncthreads();
        }

        // ---- chunk boundary: flush outputs, prefetch chunk ci+2 ----
        // obuf[cb] is complete (post-barrier); next chunk writes obuf[cb^1],
        // so the flush read cannot race.
        const vf4 ov = *(const vf4*)&obuf[cb][tid * 4];
        *(vf4*)(obase + (size_t)ci * CH * HH + tid * 4) = ov;
        if (ci + 2 < NCH) {
            rpf = LD4(xbase + (size_t)(ci + 2) * CH * HH + tid * 4);
        }
        // These globals drain at the next chunk's first barrier — once per
        // 8 steps, overlapped with step-0 compute (~50 cyc/step amortized).
    }
}

extern "C" void kernel_launch(void* const* d_in, const int* in_sizes, int n_in,
                              void* d_out, int out_size, void* d_ws, size_t ws_size,
                              hipStream_t stream) {
    const float* x    = (const float*)d_in[0];
    const float* W_ih = (const float*)d_in[1];
    const float* W_hh = (const float*)d_in[2];
    const float* b_ih = (const float*)d_in[3];
    const float* b_hh = (const float*)d_in[4];
    float* out = (float*)d_out;

    const size_t xp_bytes = (size_t)BB * TT * HH * sizeof(float);   // 64 MiB
    // Aliased fallback stays correct: xp chunk k is loaded (2 chunks ahead)
    // strictly before out chunk k is flushed.
    float* xp = (ws_size >= xp_bytes) ? (float*)d_ws : out;

    xproj_kernel<<<dim3(512 * 2), dim3(256), 0, stream>>>(x, W_ih, b_ih, xp);
    rnn_kernel<<<dim3(BB), dim3(512), 0, stream>>>(W_hh, b_hh, xp, out);
}

// Round 6
// 780.966 us; speedup vs baseline: 1.1737x; 1.0035x over previous
//
#include <hip/hip_runtime.h>

#define BB 64
#define TT 1024
#define DD 256
#define HH 256
#define CH 8             // timesteps per LDS chunk
#define NCH (TT / CH)    // 128 chunks

typedef float vf4 __attribute__((ext_vector_type(4)));
typedef float vf2 __attribute__((ext_vector_type(2)));
struct alignas(16) v2x2 { vf2 lo, hi; };   // one 16-B load, two pk-operands

#define LD4(p) (*(const vf4*)(p))
#define LD2(p) (*(const vf2*)(p))
#define LDW(p) (*(const v2x2*)(p))

// tanh(x) = 1 - 2/(e^{2x}+1); saturates correctly for large |x|.
__device__ __forceinline__ float fast_tanh(float x) {
    float e = __expf(2.0f * x);
    return 1.0f - 2.0f / (e + 1.0f);
}

// float2 FMA: selects v_pk_fma_f32 on gfx950 (exact fp32, 2x rate).
#define PKFMA(acc, aa, bb) acc = __builtin_elementwise_fma((aa), (bb), (acc))

// dst = src + dpp_shuffle(src). VALU-pipe cross-lane (no LDS traffic).
// CTRL: 0xB1 quad_perm xor1, 0x4E quad_perm xor2, 0x124 row_ror:4, 0x128 row_ror:8.
#define DPPADD(dst, src, CTRL) {                                                   \
    int _di = __builtin_amdgcn_update_dpp(0, __float_as_int(src), CTRL, 0xF, 0xF, true); \
    dst = (src) + __int_as_float(_di); }

// NOTE: macro params must NOT be named x/y/z/w (component-accessor capture).
#define FMR(rr, bb, ss)                   \
    rr.x = fmaf((ss), (bb).x, rr.x);      \
    rr.y = fmaf((ss), (bb).y, rr.y);      \
    rr.z = fmaf((ss), (bb).z, rr.z);      \
    rr.w = fmaf((ss), (bb).w, rr.w)

// ---------------------------------------------------------------------------
// Phase 1 (unchanged, ~160 us): xp = x * W_ih^T + b_ih, tiled GEMM.
// ---------------------------------------------------------------------------
#define BKb 32
#define LDP 132

__global__ __attribute__((amdgpu_flat_work_group_size(256, 256),
                          amdgpu_waves_per_eu(4, 4)))
void xproj_kernel(const float* __restrict__ x, const float* __restrict__ W_ih,
                  const float* __restrict__ b_ih, float* __restrict__ xp)
{
    __shared__ float As[BKb][LDP];
    __shared__ float Bs[BKb][LDP];

    const int tid = threadIdx.x;
    const int nb = blockIdx.x & 1;
    const int mb = blockIdx.x >> 1;
    const int m0 = mb * 128;
    const int n0 = nb * 128;

    const int sr = tid >> 3;
    const int sk = (tid & 7) * 4;

    const int tx = tid & 15;
    const int ty = tid >> 4;
    const int ma = ty * 4, mh = 64 + ty * 4;
    const int na = tx * 4, nh = 64 + tx * 4;

    vf4 ra0 = 0, ra1 = 0, ra2 = 0, ra3 = 0, ra4 = 0, ra5 = 0, ra6 = 0, ra7 = 0;
    vf4 rb0 = 0, rb1 = 0, rb2 = 0, rb3 = 0, rb4 = 0, rb5 = 0, rb6 = 0, rb7 = 0;

    for (int k0 = 0; k0 < DD; k0 += BKb) {
        #pragma unroll
        for (int g = 0; g < 4; ++g) {
            const int r = sr + g * 32;
            const vf4 v = LD4(x + (size_t)(m0 + r) * DD + k0 + sk);
            As[sk + 0][r] = v.x; As[sk + 1][r] = v.y;
            As[sk + 2][r] = v.z; As[sk + 3][r] = v.w;
        }
        #pragma unroll
        for (int g = 0; g < 4; ++g) {
            const int n = sr + g * 32;
            const vf4 v = LD4(W_ih + (size_t)(n0 + n) * DD + k0 + sk);
            Bs[sk + 0][n] = v.x; Bs[sk + 1][n] = v.y;
            Bs[sk + 2][n] = v.z; Bs[sk + 3][n] = v.w;
        }
        __syncthreads();

        #pragma unroll
        for (int kk = 0; kk < BKb; ++kk) {
            const vf4 alo = LD4(&As[kk][ma]);
            const vf4 ahi = LD4(&As[kk][mh]);
            const vf4 bl  = LD4(&Bs[kk][na]);
            const vf4 bh  = LD4(&Bs[kk][nh]);
            FMR(ra0, bl, alo.x); FMR(rb0, bh, alo.x);
            FMR(ra1, bl, alo.y); FMR(rb1, bh, alo.y);
            FMR(ra2, bl, alo.z); FMR(rb2, bh, alo.z);
            FMR(ra3, bl, alo.w); FMR(rb3, bh, alo.w);
            FMR(ra4, bl, ahi.x); FMR(rb4, bh, ahi.x);
            FMR(ra5, bl, ahi.y); FMR(rb5, bh, ahi.y);
            FMR(ra6, bl, ahi.z); FMR(rb6, bh, ahi.z);
            FMR(ra7, bl, ahi.w); FMR(rb7, bh, ahi.w);
        }
        __syncthreads();
    }

    const vf4 bia = LD4(b_ih + n0 + na);
    const vf4 bib = LD4(b_ih + n0 + nh);

    #define STORE_ROW(m, rA, rB)                                   \
        {                                                          \
            float* outp = xp + (size_t)(m0 + (m)) * HH + n0;       \
            *(vf4*)(outp + na) = rA + bia;                         \
            *(vf4*)(outp + nh) = rB + bib;                         \
        }
    STORE_ROW(ma + 0, ra0, rb0); STORE_ROW(ma + 1, ra1, rb1);
    STORE_ROW(ma + 2, ra2, rb2); STORE_ROW(ma + 3, ra3, rb3);
    STORE_ROW(mh + 0, ra4, rb4); STORE_ROW(mh + 1, ra5, rb5);
    STORE_ROW(mh + 2, ra6, rb6); STORE_ROW(mh + 3, ra7, rb7);
    #undef STORE_ROW
}

// ---------------------------------------------------------------------------
// Phase 2: recurrence, one WG per batch (64 WGs, 512 threads).
// G=8 outputs/lane x L=16 k-elems/lane; chunk-staged xp/out through LDS.
// R7 result: VGPR=88 (weights NOT resident), dynamic VALU ~2x static =>
// allocator parks the 128 weight floats in AGPRs (VOP3P can't source AGPRs
// => v_accvgpr_read per use per step). Theory under test: peak register
// pressure from the FULLY-unrolled 8-step body (hoisted xp/h reads + DPP
// temps) is what pushes weights out of arch VGPRs. Fixes:
//   - #pragma unroll 2 on the step loop (keeps hbuf parity static; kills
//     the pressure spike).
//   - asm pins ONCE before the chunk loop (a "+v" pin is an opaque redef =>
//     remat inside the loop is illegal; per-chunk pins and their copy
//     traffic deleted).
// (Third submission of this experiment — R4/R5 died to container-level
// infra failures; the diff vs the clean-running R3 kernel is benign.)
// ---------------------------------------------------------------------------
__global__ __attribute__((amdgpu_flat_work_group_size(512, 512),
                          amdgpu_waves_per_eu(2, 2)))
void rnn_kernel(const float* __restrict__ W_hh, const float* __restrict__ b_hh,
                const float* __restrict__ xpin, float* __restrict__ hout)
{
    const int tid = threadIdx.x;
    const int jg = tid >> 4;          // 0..31: group of 8 outputs
    const int c  = tid & 15;          // 0..15: k-chunk (16 floats)
    const int j0 = jg * 8;
    const int jmine = j0 + (c & 7);   // the output this lane finalizes (writers: c<8)
    const int b = blockIdx.x;

    __shared__ float hbuf[2][16 * 20];     // h[k] at word (k>>4)*20 + (k&15)
    __shared__ float xchk[2][CH * HH];     // xp chunk double-buffer (2 x 8 KB)
    __shared__ float obuf[2][CH * HH];     // output staging double-buffer (2 x 8 KB)

    // Weights: 8 rows (j0..j0+7) x 16 cols (c*16..c*16+15) = 128 floats/lane.
    v2x2 w[8][4];
    #pragma unroll
    for (int r = 0; r < 8; ++r) {
        const float* wr = W_hh + (size_t)(j0 + r) * HH + c * 16;
        w[r][0] = LDW(wr + 0);  w[r][1] = LDW(wr + 4);
        w[r][2] = LDW(wr + 8);  w[r][3] = LDW(wr + 12);
    }
    const float bias = b_hh[jmine];

    // Pin weights ONCE (opaque redefinition => loads cannot be
    // rematerialized/sunk into the loop; no per-chunk copy traffic).
    asm volatile("" : "+v"(w[0][0].lo), "+v"(w[0][0].hi), "+v"(w[0][1].lo), "+v"(w[0][1].hi),
                      "+v"(w[0][2].lo), "+v"(w[0][2].hi), "+v"(w[0][3].lo), "+v"(w[0][3].hi),
                      "+v"(w[1][0].lo), "+v"(w[1][0].hi), "+v"(w[1][1].lo), "+v"(w[1][1].hi),
                      "+v"(w[1][2].lo), "+v"(w[1][2].hi), "+v"(w[1][3].lo), "+v"(w[1][3].hi));
    asm volatile("" : "+v"(w[2][0].lo), "+v"(w[2][0].hi), "+v"(w[2][1].lo), "+v"(w[2][1].hi),
                      "+v"(w[2][2].lo), "+v"(w[2][2].hi), "+v"(w[2][3].lo), "+v"(w[2][3].hi),
                      "+v"(w[3][0].lo), "+v"(w[3][0].hi), "+v"(w[3][1].lo), "+v"(w[3][1].hi),
                      "+v"(w[3][2].lo), "+v"(w[3][2].hi), "+v"(w[3][3].lo), "+v"(w[3][3].hi));
    asm volatile("" : "+v"(w[4][0].lo), "+v"(w[4][0].hi), "+v"(w[4][1].lo), "+v"(w[4][1].hi),
                      "+v"(w[4][2].lo), "+v"(w[4][2].hi), "+v"(w[4][3].lo), "+v"(w[4][3].hi),
                      "+v"(w[5][0].lo), "+v"(w[5][0].hi), "+v"(w[5][1].lo), "+v"(w[5][1].hi),
                      "+v"(w[5][2].lo), "+v"(w[5][2].hi), "+v"(w[5][3].lo), "+v"(w[5][3].hi));
    asm volatile("" : "+v"(w[6][0].lo), "+v"(w[6][0].hi), "+v"(w[6][1].lo), "+v"(w[6][1].hi),
                      "+v"(w[6][2].lo), "+v"(w[6][2].hi), "+v"(w[6][3].lo), "+v"(w[6][3].hi),
                      "+v"(w[7][0].lo), "+v"(w[7][0].hi), "+v"(w[7][1].lo), "+v"(w[7][1].hi),
                      "+v"(w[7][2].lo), "+v"(w[7][2].hi), "+v"(w[7][3].lo), "+v"(w[7][3].hi));

    const float* xbase = xpin + (size_t)b * TT * HH;
    float*       obase = hout + (size_t)b * TT * HH;
    const int haddr = ((jmine >> 4) * 20) + (jmine & 15);   // LDS slot for jmine

    // ---- prologue: chunk 0 into LDS, chunk 1 into registers (in flight) ----
    vf4 rpf = LD4(xbase + tid * 4);               // chunk 0 (2048 floats, 4/thread)
    if (tid < 320) hbuf[0][tid] = 0.0f;           // h_0 = 0 (pads incl.)
    *(vf4*)&xchk[0][tid * 4] = rpf;               // (compiler inserts vmcnt wait)
    rpf = LD4(xbase + CH * HH + tid * 4);         // chunk 1, stays in flight
    __syncthreads();

    for (int ci = 0; ci < NCH; ++ci) {
        const int cb = ci & 1;

        const float* xc = &xchk[cb][0];
        float*       ob = &obuf[cb][0];

        // unroll 2: enough to make hbuf[s&1] parity compile-time, small
        // enough to keep peak register pressure low so weights stay in
        // arch VGPRs (unroll 8 pushed them into AGPRs => copy churn).
        #pragma unroll 2
        for (int s = 0; s < CH; ++s) {
            // xp for this step: LDS read.
            const float xpb = xc[s * HH + jmine] + bias;

            const float* hc = &hbuf[s & 1][c * 20];
            const v2x2 h0 = LDW(hc + 0), h1 = LDW(hc + 4),
                       h2 = LDW(hc + 8), h3 = LDW(hc + 12);

            vf2 a0 = {0.f, 0.f}, a1 = {0.f, 0.f}, a2 = {0.f, 0.f}, a3 = {0.f, 0.f};
            vf2 a4 = {0.f, 0.f}, a5 = {0.f, 0.f}, a6 = {0.f, 0.f}, a7 = {0.f, 0.f};
            PKFMA(a0, w[0][0].lo, h0.lo); PKFMA(a0, w[0][0].hi, h0.hi);
            PKFMA(a0, w[0][1].lo, h1.lo); PKFMA(a0, w[0][1].hi, h1.hi);
            PKFMA(a0, w[0][2].lo, h2.lo); PKFMA(a0, w[0][2].hi, h2.hi);
            PKFMA(a0, w[0][3].lo, h3.lo); PKFMA(a0, w[0][3].hi, h3.hi);
            PKFMA(a1, w[1][0].lo, h0.lo); PKFMA(a1, w[1][0].hi, h0.hi);
            PKFMA(a1, w[1][1].lo, h1.lo); PKFMA(a1, w[1][1].hi, h1.hi);
            PKFMA(a1, w[1][2].lo, h2.lo); PKFMA(a1, w[1][2].hi, h2.hi);
            PKFMA(a1, w[1][3].lo, h3.lo); PKFMA(a1, w[1][3].hi, h3.hi);
            PKFMA(a2, w[2][0].lo, h0.lo); PKFMA(a2, w[2][0].hi, h0.hi);
            PKFMA(a2, w[2][1].lo, h1.lo); PKFMA(a2, w[2][1].hi, h1.hi);
            PKFMA(a2, w[2][2].lo, h2.lo); PKFMA(a2, w[2][2].hi, h2.hi);
            PKFMA(a2, w[2][3].lo, h3.lo); PKFMA(a2, w[2][3].hi, h3.hi);
            PKFMA(a3, w[3][0].lo, h0.lo); PKFMA(a3, w[3][0].hi, h0.hi);
            PKFMA(a3, w[3][1].lo, h1.lo); PKFMA(a3, w[3][1].hi, h1.hi);
            PKFMA(a3, w[3][2].lo, h2.lo); PKFMA(a3, w[3][2].hi, h2.hi);
            PKFMA(a3, w[3][3].lo, h3.lo); PKFMA(a3, w[3][3].hi, h3.hi);
            PKFMA(a4, w[4][0].lo, h0.lo); PKFMA(a4, w[4][0].hi, h0.hi);
            PKFMA(a4, w[4][1].lo, h1.lo); PKFMA(a4, w[4][1].hi, h1.hi);
            PKFMA(a4, w[4][2].lo, h2.lo); PKFMA(a4, w[4][2].hi, h2.hi);
            PKFMA(a4, w[4][3].lo, h3.lo); PKFMA(a4, w[4][3].hi, h3.hi);
            PKFMA(a5, w[5][0].lo, h0.lo); PKFMA(a5, w[5][0].hi, h0.hi);
            PKFMA(a5, w[5][1].lo, h1.lo); PKFMA(a5, w[5][1].hi, h1.hi);
            PKFMA(a5, w[5][2].lo, h2.lo); PKFMA(a5, w[5][2].hi, h2.hi);
            PKFMA(a5, w[5][3].lo, h3.lo); PKFMA(a5, w[5][3].hi, h3.hi);
            PKFMA(a6, w[6][0].lo, h0.lo); PKFMA(a6, w[6][0].hi, h0.hi);
            PKFMA(a6, w[6][1].lo, h1.lo); PKFMA(a6, w[6][1].hi, h1.hi);
            PKFMA(a6, w[6][2].lo, h2.lo); PKFMA(a6, w[6][2].hi, h2.hi);
            PKFMA(a6, w[6][3].lo, h3.lo); PKFMA(a6, w[6][3].hi, h3.hi);
            PKFMA(a7, w[7][0].lo, h0.lo); PKFMA(a7, w[7][0].hi, h0.hi);
            PKFMA(a7, w[7][1].lo, h1.lo); PKFMA(a7, w[7][1].hi, h1.hi);
            PKFMA(a7, w[7][2].lo, h2.lo); PKFMA(a7, w[7][2].hi, h2.hi);
            PKFMA(a7, w[7][3].lo, h3.lo); PKFMA(a7, w[7][3].hi, h3.hi);

            const float s0 = a0.x + a0.y, s1 = a1.x + a1.y,
                        s2 = a2.x + a2.y, s3 = a3.x + a3.y,
                        s4 = a4.x + a4.y, s5 = a5.x + a5.y,
                        s6 = a6.x + a6.y, s7 = a7.x + a7.y;

            // 16-lane reduce of 8 outputs: xor1 +sel, xor2 +sel, ror4 +sel, ror8.
            float t0, t1, t2, t3, t4, t5, t6, t7;
            DPPADD(t0, s0, 0xB1); DPPADD(t1, s1, 0xB1);
            DPPADD(t2, s2, 0xB1); DPPADD(t3, s3, 0xB1);
            DPPADD(t4, s4, 0xB1); DPPADD(t5, s5, 0xB1);
            DPPADD(t6, s6, 0xB1); DPPADD(t7, s7, 0xB1);
            const float p0 = (c & 1) ? t1 : t0;
            const float p1 = (c & 1) ? t3 : t2;
            const float p2 = (c & 1) ? t5 : t4;
            const float p3 = (c & 1) ? t7 : t6;
            float u0, u1, u2, u3;
            DPPADD(u0, p0, 0x4E); DPPADD(u1, p1, 0x4E);
            DPPADD(u2, p2, 0x4E); DPPADD(u3, p3, 0x4E);
            const float v0 = (c & 2) ? u1 : u0;
            const float v1 = (c & 2) ? u3 : u2;
            float q0, q1;
            DPPADD(q0, v0, 0x124); DPPADD(q1, v1, 0x124);
            float vfin = (c & 4) ? q1 : q0;
            DPPADD(vfin, vfin, 0x128);

            // Stage next xp chunk into the other LDS buffer (once per chunk;
            // rpf was loaded ~8 steps ago, so the vmcnt wait here is free).
            if (s == CH - 1 && ci != NCH - 1) {
                *(vf4*)&xchk[cb ^ 1][tid * 4] = rpf;
            }

            const float hn = fast_tanh(vfin + xpb);
            if (c < 8) {
                hbuf[1 - (s & 1)][haddr] = hn;        // h for next step
                ob[s * HH + jmine] = hn;              // output staging (LDS)
            }
            __syncthreads();
        }

        // ---- chunk boundary: flush outputs, prefetch chunk ci+2 ----
        // obuf[cb] is complete (post-barrier); next chunk writes obuf[cb^1],
        // so the flush read cannot race.
        const vf4 ov = *(const vf4*)&obuf[cb][tid * 4];
        *(vf4*)(obase + (size_t)ci * CH * HH + tid * 4) = ov;
        if (ci + 2 < NCH) {
            rpf = LD4(xbase + (size_t)(ci + 2) * CH * HH + tid * 4);
        }
        // These globals drain at the next chunk's first barrier — once per
        // 8 steps, overlapped with step-0 compute (~50 cyc/step amortized).
    }
}

extern "C" void kernel_launch(void* const* d_in, const int* in_sizes, int n_in,
                              void* d_out, int out_size, void* d_ws, size_t ws_size,
                              hipStream_t stream) {
    const float* x    = (const float*)d_in[0];
    const float* W_ih = (const float*)d_in[1];
    const float* W_hh = (const float*)d_in[2];
    const float* b_ih = (const float*)d_in[3];
    const float* b_hh = (const float*)d_in[4];
    float* out = (float*)d_out;

    const size_t xp_bytes = (size_t)BB * TT * HH * sizeof(float);   // 64 MiB
    // Aliased fallback stays correct: xp chunk k is loaded (2 chunks ahead)
    // strictly before out chunk k is flushed.
    float* xp = (ws_size >= xp_bytes) ? (float*)d_ws : out;

    xproj_kernel<<<dim3(512 * 2), dim3(256), 0, stream>>>(x, W_ih, b_ih, xp);
    rnn_kernel<<<dim3(BB), dim3(512), 0, stream>>>(W_hh, b_hh, xp, out);
}